// Round 15
// baseline (393.741 us; speedup 1.0000x reference)
//
#include <hip/hip_runtime.h>
#include <hip/hip_bf16.h>

typedef short short8 __attribute__((ext_vector_type(8)));
typedef short short4v __attribute__((ext_vector_type(4)));
typedef float f32x4 __attribute__((ext_vector_type(4)));

#define SHIFT_ 32

__device__ __forceinline__ float bf2f(unsigned short u) {
    union { unsigned int i; float f; } z; z.i = ((unsigned)u) << 16; return z.f;
}
__device__ __forceinline__ unsigned short f2bf(float f) {
    union { float f; unsigned int i; } z; z.f = f;
    unsigned int x = z.i;
    x += 0x7fffu + ((x >> 16) & 1u);   // round-to-nearest-even
    return (unsigned short)(x >> 16);
}

// ------- fp32 -> bf16 weight conversion, all 4 weights in one dispatch ----
__global__ __launch_bounds__(256)
void f2bf_all(const float* __restrict__ s0, const float* __restrict__ s1,
              const float* __restrict__ s2, const float* __restrict__ s3,
              unsigned short* __restrict__ dst) {
    int b = blockIdx.x;
    const float* src; int off;
    if (b < 768)       { src = s0; off = b * 1024; }
    else if (b < 1024) { src = s1; off = (b - 768) * 1024; }
    else if (b < 2048) { src = s2; off = (b - 1024) * 1024; }
    else               { src = s3; off = (b - 2048) * 1024; }
    int i = off + threadIdx.x * 4;
    f32x4 v = *(const f32x4*)(src + i);
    short4v o;
#pragma unroll
    for (int j = 0; j < 4; j++) o[j] = (short)f2bf(v[j]);
    *(short4v*)(dst + (size_t)b * 1024 + threadIdx.x * 4) = o;
}

// ---------------- LayerNorm (+roll on source index), bf16 out -------------
template <bool BF16IN>
__global__ __launch_bounds__(256)
void ln_kernel(const void* __restrict__ srcv,
               const float* __restrict__ gam,
               const float* __restrict__ bet,
               unsigned short* __restrict__ dst, int roll) {
    int wid = threadIdx.x >> 6, lane = threadIdx.x & 63;
    int m = (blockIdx.x << 2) + wid;              // output row in [0, 32768)
    int b = m >> 12, s = m & 4095;
    int ms = (b << 12) | ((s + roll) & 4095);     // source row
    float f[8], sum = 0.f, sq = 0.f;
    if (BF16IN) {
        short8 v = *(const short8*)((const unsigned short*)srcv + (size_t)ms * 512 + lane * 8);
#pragma unroll
        for (int j = 0; j < 8; j++) f[j] = bf2f((unsigned short)v[j]);
    } else {
        const float* p = (const float*)srcv + (size_t)ms * 512 + lane * 8;
        f32x4 v0 = *(const f32x4*)p;
        f32x4 v1 = *(const f32x4*)(p + 4);
#pragma unroll
        for (int j = 0; j < 4; j++) { f[j] = v0[j]; f[j + 4] = v1[j]; }
    }
#pragma unroll
    for (int j = 0; j < 8; j++) { sum += f[j]; sq += f[j] * f[j]; }
#pragma unroll
    for (int o = 1; o < 64; o <<= 1) { sum += __shfl_xor(sum, o); sq += __shfl_xor(sq, o); }
    float mean = sum * (1.f / 512.f);
    float rstd = rsqrtf(sq * (1.f / 512.f) - mean * mean + 1e-5f);
    const float* gp = gam + lane * 8;
    const float* bp = bet + lane * 8;
    f32x4 g0 = *(const f32x4*)gp, g1 = *(const f32x4*)(gp + 4);
    f32x4 b0 = *(const f32x4*)bp, b1 = *(const f32x4*)(bp + 4);
    short8 ov;
#pragma unroll
    for (int j = 0; j < 4; j++) {
        ov[j]     = (short)f2bf((f[j] - mean) * rstd * g0[j] + b0[j]);
        ov[j + 4] = (short)f2bf((f[j + 4] - mean) * rstd * g1[j] + b1[j]);
    }
    *(short8*)(dst + (size_t)m * 512 + lane * 8) = ov;
}

// ------ 128xBN MFMA GEMM, 3-buffer rotation, ONE barrier/K-step ----------
// BN=128: 4 waves x (64x64), acc 4x4, LDS 48KB, 3 blocks/CU (launch min 3).
// BN=64 : 4 waves x (64x32), acc 4x2, LDS 36KB, 4 blocks/CU (launch min 4)
//         -> for N=512 GEMMs: grid 2048 = exactly 2 full scheduling rounds
//         (fixes R14's 1.33-round tail on FC2/proj, occupancy 21%).
// EPI: 0 = none, 1 = exact GELU, 2 = +roll(+32) residual (extra = x fp32),
//      3 = +residual (extra = x1, fp32 or bf16 per RESBF16)
template <int N, int K, int EPI, bool OUTF32, bool RESBF16, int BN>
__global__ __launch_bounds__(256, BN == 64 ? 4 : 3)
void gemm_kernel(const unsigned short* __restrict__ A,
                 const unsigned short* __restrict__ Wt,
                 const float* __restrict__ bias,
                 void* __restrict__ outv,
                 const void* __restrict__ extra, int nwg) {
    constexpr int BELEM = BN * 32;                    // B-buf elems
    constexpr int NI = BN / 32;                       // 4 or 2 col frags/wave
    __shared__ __attribute__((aligned(16))) unsigned short smem[12288 + 3 * BELEM];
    // T1: XCD-aware swizzle (grids are multiples of 8; bijective)
    int cpx = nwg >> 3;
    int bid = (blockIdx.x & 7) * cpx + (blockIdx.x >> 3);
    const int nbx = N / BN;
    int bcol = bid % nbx, brow = bid / nbx;
    int m0 = brow << 7, n0 = bcol * BN;
    int t = threadIdx.x, lane = t & 63;
    int wid = t >> 6;
    int wr = (wid >> 1) << 6;                         // wave row block (0/64)
    int wc = (wid & 1) * (BN / 2);                    // wave col block
    int rsel = lane & 15, qq = lane >> 4;
    int slotr = ((qq ^ (rsel & 3)) << 3);             // swizzled 16B slot

    // staging chunks: A has 2/thread; B has 2 (BN=128) or 1 (BN=64)
    int r0 = t >> 2;
    int s0 = (((t & 3) ^ (r0 & 3)) << 3);
    int r1 = (t + 256) >> 2;
    int s1 = ((((t + 256) & 3) ^ (r1 & 3)) << 3);

#define SAb(b) (smem + (b) * 4096)
#define SBb(b) (smem + 12288 + (b) * BELEM)
#define GLD(src, dst) __builtin_amdgcn_global_load_lds(                         \
        (const __attribute__((address_space(1))) void*)(src),                  \
        (__attribute__((address_space(3))) void*)(dst), 16, 0, 0)

    auto STAGE = [&](int buf, int k0) {
        GLD(A + (size_t)(m0 + r0) * K + k0 + s0, SAb(buf) + t * 8);
        GLD(Wt + (size_t)(n0 + r0 % BN) * K + k0 + s0, SBb(buf) + (t % (BELEM / 8)) * 8);
        GLD(A + (size_t)(m0 + r1) * K + k0 + s1, SAb(buf) + (t + 256) * 8);
        if (BN == 128)
            GLD(Wt + (size_t)(n0 + r1) * K + k0 + s1, SBb(buf) + (t + 256) * 8);
    };

    f32x4 zero4 = {0.f, 0.f, 0.f, 0.f};
    f32x4 acc[4][NI];
#pragma unroll
    for (int mi = 0; mi < 4; mi++)
#pragma unroll
        for (int ni = 0; ni < NI; ni++) acc[mi][ni] = zero4;

    const int NT = K / 32;
    STAGE(0, 0);               // tile 0
    STAGE(1, 32);              // tile 1 outstanding
    for (int tt = 0; tt < NT; tt++) {
        int cur = tt % 3;
        if (tt < NT - 1) {
            if (BN == 128) asm volatile("s_waitcnt vmcnt(4)" ::: "memory");
            else           asm volatile("s_waitcnt vmcnt(3)" ::: "memory");
        } else {
            asm volatile("s_waitcnt vmcnt(0)" ::: "memory");
        }
        __builtin_amdgcn_sched_barrier(0);
        __builtin_amdgcn_s_barrier();          // tile tt ready; all waves past tt-1
        __builtin_amdgcn_sched_barrier(0);
        if (tt + 2 < NT) STAGE((tt + 2) % 3, (tt + 2) * 32);   // refill buf read at tt-1
        short8 af[4], bf4[NI];
#pragma unroll
        for (int mi = 0; mi < 4; mi++)
            af[mi] = *(const short8*)(SAb(cur) + (wr + mi * 16 + rsel) * 32 + slotr);
#pragma unroll
        for (int ni = 0; ni < NI; ni++)
            bf4[ni] = *(const short8*)(SBb(cur) + (wc + ni * 16 + rsel) * 32 + slotr);
#pragma unroll
        for (int mi = 0; mi < 4; mi++)
#pragma unroll
            for (int ni = 0; ni < NI; ni++)
                acc[mi][ni] = __builtin_amdgcn_mfma_f32_16x16x32_bf16(af[mi], bf4[ni], acc[mi][ni], 0, 0, 0);
    }
    __builtin_amdgcn_s_barrier();              // all reads done before LDS reuse
#undef GLD

    // epilogue: C/D layout col = lane&15, row = (lane>>4)*4 + j  [m89/m91]
    int jbase = qq << 2;
    constexpr int WCOLS = BN / 2;              // wave tile cols (64 or 32)
    constexpr int GMASK = (BN == 128) ? 3 : 1; // col-group swizzle mask
    if (!OUTF32) {
        // per-wave private 64xWCOLS LDS tile (wave-local)
        unsigned short* ep = smem + wid * (64 * WCOLS);
#pragma unroll
        for (int ni = 0; ni < NI; ni++) {
            float bv = bias[n0 + wc + ni * 16 + rsel];
            int cswz = ((ni ^ (qq & GMASK)) << 4) + rsel;
#pragma unroll
            for (int mi = 0; mi < 4; mi++)
#pragma unroll
                for (int j = 0; j < 4; j++) {
                    float v = acc[mi][ni][j] + bv;
                    if (EPI == 1) v = 0.5f * v * (1.f + erff(v * 0.70710678118654752f));
                    ep[(mi * 16 + jbase + j) * WCOLS + cswz] = f2bf(v);
                }
        }
        unsigned short* outp = (unsigned short*)outv;
        constexpr int CPR = WCOLS / 8;         // 8B-chunks per row (8 or 4)
#pragma unroll
        for (int it = 0; it < WCOLS / 8; it++) {
            int chunk = it * 64 + lane;
            int rr = chunk / CPR, c8 = (chunk % CPR) << 3;
            int g = (rr >> 2) & GMASK;
            short8 vv = *(const short8*)(ep + rr * WCOLS + (c8 ^ (g << 4)));
            int grow = m0 + wr + rr, gcol = n0 + wc + c8;
            if (EPI == 2) {
                int orow = (grow & ~4095) | ((grow + SHIFT_) & 4095);
                const float* xr = (const float*)extra + (size_t)orow * N + gcol;
                f32x4 x0 = *(const f32x4*)xr, x1v = *(const f32x4*)(xr + 4);
                short8 ov;
#pragma unroll
                for (int e = 0; e < 4; e++) {
                    ov[e]     = (short)f2bf(bf2f((unsigned short)vv[e]) + x0[e]);
                    ov[e + 4] = (short)f2bf(bf2f((unsigned short)vv[e + 4]) + x1v[e]);
                }
                *(short8*)(outp + (size_t)orow * N + gcol) = ov;
            } else {
                *(short8*)(outp + (size_t)grow * N + gcol) = vv;
            }
        }
    } else {
        // fp32: 16 lanes x 4B = 64B contiguous runs — sector-aligned
#pragma unroll
        for (int ni = 0; ni < NI; ni++) {
            int gcol = n0 + wc + ni * 16 + rsel;
            float bv = bias[gcol];
#pragma unroll
            for (int mi = 0; mi < 4; mi++) {
#pragma unroll
                for (int j = 0; j < 4; j++) {
                    int grow = m0 + wr + mi * 16 + jbase + j;
                    float v = acc[mi][ni][j] + bv;
                    size_t oidx;
                    if (EPI == 2) {
                        int orow = (grow & ~4095) | ((grow + SHIFT_) & 4095);  // roll +32
                        oidx = (size_t)orow * N + gcol;
                        v += ((const float*)extra)[oidx];
                    } else {
                        oidx = (size_t)grow * N + gcol;
                        if (EPI == 3)
                            v += RESBF16 ? bf2f(((const unsigned short*)extra)[oidx])
                                         : ((const float*)extra)[oidx];
                    }
                    ((float*)outv)[oidx] = v;
                }
            }
        }
    }
#undef SAb
#undef SBb
}

// ---------------- MFMA window attention: one wave per (window, head) ------
// Block = 4 consecutive heads of ONE window -> 128 contiguous output cols;
// output staged in LDS and stored as 256B segments (write-amp fix).
__global__ __launch_bounds__(256, 2)
void attn_kernel(const unsigned short* __restrict__ qkv,
                 const float* __restrict__ relb,
                 unsigned short* __restrict__ obuf) {
    __shared__ __attribute__((aligned(16))) unsigned short Pl[4][64 * 72];
    __shared__ __attribute__((aligned(16))) unsigned short Vt[4][32 * 72];
    __shared__ float biasd[4][128];
    int t = threadIdx.x;
    int wid = t >> 6, lane = t & 63;
    int win = blockIdx.x >> 2;            // 512 windows
    int h0 = (blockIdx.x & 3) << 2;       // first head of this block
    int h = h0 + wid;
    const unsigned short* base = qkv + (size_t)win * 98304 + h * 32;

    float* bd = biasd[wid];
    bd[lane] = relb[lane * 16 + h];
    if (lane < 63) bd[lane + 64] = relb[(lane + 64) * 16 + h];

    int rsel = lane & 15, ksel = (lane >> 4) << 3;
    short8 qf[4], kf[4];
#pragma unroll
    for (int i = 0; i < 4; i++) {
        qf[i] = *(const short8*)(base + (size_t)(i * 16 + rsel) * 1536 + ksel);
        kf[i] = *(const short8*)(base + (size_t)(i * 16 + rsel) * 1536 + 512 + ksel);
    }
    f32x4 zero4 = {0.f, 0.f, 0.f, 0.f};
    f32x4 accS[4][4];
#pragma unroll
    for (int mi = 0; mi < 4; mi++)
#pragma unroll
        for (int ni = 0; ni < 4; ni++) accS[mi][ni] = zero4;
#pragma unroll
    for (int mi = 0; mi < 4; mi++)
#pragma unroll
        for (int ni = 0; ni < 4; ni++)
            accS[mi][ni] = __builtin_amdgcn_mfma_f32_16x16x32_bf16(qf[mi], kf[ni], accS[mi][ni], 0, 0, 0);

    // stage V^T into LDS: vt[d][k] = v[k][d], padded stride 72
    unsigned short* vt = Vt[wid];
#pragma unroll 8
    for (int it = 0; it < 32; it++) {
        int idx = (it << 6) + lane;
        int vr = idx >> 5, vd = idx & 31;
        vt[vd * 72 + vr] = base[(size_t)vr * 1536 + 1024 + vd];
    }
    __syncthreads();

    const float scale = 0.17677669529663687f;  // 1/sqrt(32)
    bool masked = ((win & 63) == 63);
    int jbase = (lane >> 4) << 2;
    float rs[4][4];
#pragma unroll
    for (int mi = 0; mi < 4; mi++) {
#pragma unroll
        for (int ni = 0; ni < 4; ni++) {
            int colb = ni * 16 + rsel;
#pragma unroll
            for (int j = 0; j < 4; j++) {
                int row = mi * 16 + jbase + j;
                float v = accS[mi][ni][j] * scale + bd[row - colb + 63];
                if (masked && ((row < 32) != (colb < 32))) v -= 100.f;
                accS[mi][ni][j] = v;
            }
        }
#pragma unroll
        for (int j = 0; j < 4; j++) {
            float m = fmaxf(fmaxf(accS[mi][0][j], accS[mi][1][j]),
                            fmaxf(accS[mi][2][j], accS[mi][3][j]));
            m = fmaxf(m, __shfl_xor(m, 1));
            m = fmaxf(m, __shfl_xor(m, 2));
            m = fmaxf(m, __shfl_xor(m, 4));
            m = fmaxf(m, __shfl_xor(m, 8));
            float ssum = 0.f;
#pragma unroll
            for (int ni = 0; ni < 4; ni++) {
                float p = __expf(accS[mi][ni][j] - m);
                accS[mi][ni][j] = p; ssum += p;
            }
            ssum += __shfl_xor(ssum, 1);
            ssum += __shfl_xor(ssum, 2);
            ssum += __shfl_xor(ssum, 4);
            ssum += __shfl_xor(ssum, 8);
            rs[mi][j] = 1.f / ssum;
        }
    }
    unsigned short* pl = Pl[wid];
#pragma unroll
    for (int mi = 0; mi < 4; mi++)
#pragma unroll
        for (int ni = 0; ni < 4; ni++)
#pragma unroll
            for (int j = 0; j < 4; j++)
                pl[(mi * 16 + jbase + j) * 72 + ni * 16 + rsel] = f2bf(accS[mi][ni][j] * rs[mi][j]);
    __syncthreads();

    f32x4 accO[4][2];
#pragma unroll
    for (int mi = 0; mi < 4; mi++) { accO[mi][0] = zero4; accO[mi][1] = zero4; }
#pragma unroll
    for (int kk = 0; kk < 2; kk++) {
        short8 pa[4], vb[2];
#pragma unroll
        for (int mi = 0; mi < 4; mi++)
            pa[mi] = *(const short8*)(pl + (mi * 16 + rsel) * 72 + (kk << 5) + ksel);
#pragma unroll
        for (int ni = 0; ni < 2; ni++)
            vb[ni] = *(const short8*)(vt + (ni * 16 + rsel) * 72 + (kk << 5) + ksel);
#pragma unroll
        for (int mi = 0; mi < 4; mi++)
#pragma unroll
            for (int ni = 0; ni < 2; ni++)
                accO[mi][ni] = __builtin_amdgcn_mfma_f32_16x16x32_bf16(pa[mi], vb[ni], accO[mi][ni], 0, 0, 0);
    }
    // ---- coalesced output: stage block's 64x128 tile in LDS (reuse Pl) ----
    __syncthreads();                                   // all waves done PV-reading Pl
    unsigned short* ot = (unsigned short*)Pl;          // [64][140] padded
    int colb = wid * 32;
#pragma unroll
    for (int mi = 0; mi < 4; mi++)
#pragma unroll
        for (int ni = 0; ni < 2; ni++)
#pragma unroll
            for (int j = 0; j < 4; j++)
                ot[(mi * 16 + jbase + j) * 140 + colb + ni * 16 + rsel] = f2bf(accO[mi][ni][j]);
    __syncthreads();
    unsigned short* ob = obuf + (size_t)win * 32768 + h0 * 32;
#pragma unroll
    for (int it = 0; it < 4; it++) {
        int chunk = it * 256 + t;
        int row = chunk >> 4, c8 = (chunk & 15) << 3;
        short8 vv = *(const short8*)(ot + row * 140 + c8);
        *(short8*)(ob + (size_t)row * 512 + c8) = vv;
    }
}

extern "C" void kernel_launch(void* const* d_in, const int* in_sizes, int n_in,
                              void* d_out, int out_size, void* d_ws, size_t ws_size,
                              hipStream_t stream) {
    (void)in_sizes; (void)n_in; (void)out_size;
    const float* x       = (const float*)d_in[0];
    const float* norm1_g = (const float*)d_in[1];
    const float* norm1_b = (const float*)d_in[2];
    const float* qkv_w   = (const float*)d_in[3];
    const float* qkv_b   = (const float*)d_in[4];
    const float* rel_b   = (const float*)d_in[5];
    const float* proj_w  = (const float*)d_in[6];
    const float* proj_b  = (const float*)d_in[7];
    const float* norm2_g = (const float*)d_in[8];
    const float* norm2_b = (const float*)d_in[9];
    const float* fc1_w   = (const float*)d_in[10];
    const float* fc1_b   = (const float*)d_in[11];
    const float* fc2_w   = (const float*)d_in[12];
    const float* fc2_b   = (const float*)d_in[13];

    char* ws = (char*)d_ws;
    unsigned short* hn   = (unsigned short*)(ws);                 // 32768x512 bf16; reused: obuf, then h2
    unsigned short* qkvb = (unsigned short*)(ws + 33554432);      // 32768x1536 bf16; reused as g1
    unsigned short* obuf = hn;                                    // alias: hn dead after QKV GEMM
    unsigned short* wq   = (unsigned short*)(ws + 167772160);     // contiguous weight block (6 MB)
    unsigned short* wp   = (unsigned short*)(ws + 167772160 + 1572864);
    unsigned short* w1   = (unsigned short*)(ws + 167772160 + 1572864 + 524288);
    unsigned short* w2   = (unsigned short*)(ws + 167772160 + 1572864 + 524288 + 2097152);
    unsigned short* x1b  = (unsigned short*)(ws + 174063616);     // 33.5 MB bf16 x1 (if ws allows)
    float* x1f           = (float*)d_out;                         // fallback: x1 fp32 in d_out
    float* outf          = (float*)d_out;
    bool bf16x1 = ws_size >= 207618048ull;                        // 174 MB + 33.5 MB

    // 0. all weights fp32 -> bf16 in ONE dispatch (wq..w2 contiguous)
    f2bf_all<<<3072, 256, 0, stream>>>(qkv_w, proj_w, fc1_w, fc2_w, wq);
    // 1. h = roll(LN1(x), -32)
    ln_kernel<false><<<8192, 256, 0, stream>>>(x, norm1_g, norm1_b, hn, SHIFT_);
    // 2. qkv = h @ qkv_w^T + qkv_b   (bf16 out, BN=128)
    gemm_kernel<1536, 512, 0, false, false, 128><<<3072, 256, 0, stream>>>(hn, wq, qkv_b, qkvb, nullptr, 3072);
    // 3. windowed attention (obuf aliases hn)
    attn_kernel<<<2048, 256, 0, stream>>>(qkvb, rel_b, obuf);
    if (bf16x1) {
        // 4. x1 = x + roll(o @ proj_w^T + proj_b, +32)   (bf16 -> x1b, BN=64)
        gemm_kernel<512, 512, 2, false, false, 64><<<2048, 256, 0, stream>>>(obuf, wp, proj_b, x1b, x, 2048);
        // 5. h2 = LN2(x1b)
        ln_kernel<true><<<8192, 256, 0, stream>>>(x1b, norm2_g, norm2_b, hn, 0);
        // 6. g1 = gelu(h2 @ fc1_w^T + fc1_b)   (BN=128)
        gemm_kernel<2048, 512, 1, false, false, 128><<<4096, 256, 0, stream>>>(hn, w1, fc1_b, qkvb, nullptr, 4096);
        // 7. out = x1b + g1 @ fc2_w^T + fc2_b   (fp32 -> d_out, BN=64)
        gemm_kernel<512, 2048, 3, true, true, 64><<<2048, 256, 0, stream>>>(qkvb, w2, fc2_b, outf, x1b, 2048);
    } else {
        // fallback: x1 fp32 in d_out
        gemm_kernel<512, 512, 2, true, false, 64><<<2048, 256, 0, stream>>>(obuf, wp, proj_b, x1f, x, 2048);
        ln_kernel<false><<<8192, 256, 0, stream>>>(x1f, norm2_g, norm2_b, hn, 0);
        gemm_kernel<2048, 512, 1, false, false, 128><<<4096, 256, 0, stream>>>(hn, w1, fc1_b, qkvb, nullptr, 4096);
        gemm_kernel<512, 2048, 3, true, false, 64><<<2048, 256, 0, stream>>>(qkvb, w2, fc2_b, outf, x1f, 2048);
    }
}

// Round 16
// 380.642 us; speedup vs baseline: 1.0344x; 1.0344x over previous
//
#include <hip/hip_runtime.h>
#include <hip/hip_bf16.h>

typedef short short8 __attribute__((ext_vector_type(8)));
typedef short short4v __attribute__((ext_vector_type(4)));
typedef float f32x4 __attribute__((ext_vector_type(4)));

#define SHIFT_ 32

__device__ __forceinline__ float bf2f(unsigned short u) {
    union { unsigned int i; float f; } z; z.i = ((unsigned)u) << 16; return z.f;
}
__device__ __forceinline__ unsigned short f2bf(float f) {
    union { float f; unsigned int i; } z; z.f = f;
    unsigned int x = z.i;
    x += 0x7fffu + ((x >> 16) & 1u);   // round-to-nearest-even
    return (unsigned short)(x >> 16);
}

// ------- fp32 -> bf16 weight conversion, all 4 weights in one dispatch ----
__global__ __launch_bounds__(256)
void f2bf_all(const float* __restrict__ s0, const float* __restrict__ s1,
              const float* __restrict__ s2, const float* __restrict__ s3,
              unsigned short* __restrict__ dst) {
    int b = blockIdx.x;
    const float* src; int off;
    if (b < 768)       { src = s0; off = b * 1024; }
    else if (b < 1024) { src = s1; off = (b - 768) * 1024; }
    else if (b < 2048) { src = s2; off = (b - 1024) * 1024; }
    else               { src = s3; off = (b - 2048) * 1024; }
    int i = off + threadIdx.x * 4;
    f32x4 v = *(const f32x4*)(src + i);
    short4v o;
#pragma unroll
    for (int j = 0; j < 4; j++) o[j] = (short)f2bf(v[j]);
    *(short4v*)(dst + (size_t)b * 1024 + threadIdx.x * 4) = o;
}

// ---------------- LayerNorm (+roll on source index), bf16 out -------------
template <bool BF16IN>
__global__ __launch_bounds__(256)
void ln_kernel(const void* __restrict__ srcv,
               const float* __restrict__ gam,
               const float* __restrict__ bet,
               unsigned short* __restrict__ dst, int roll) {
    int wid = threadIdx.x >> 6, lane = threadIdx.x & 63;
    int m = (blockIdx.x << 2) + wid;              // output row in [0, 32768)
    int b = m >> 12, s = m & 4095;
    int ms = (b << 12) | ((s + roll) & 4095);     // source row
    float f[8], sum = 0.f, sq = 0.f;
    if (BF16IN) {
        short8 v = *(const short8*)((const unsigned short*)srcv + (size_t)ms * 512 + lane * 8);
#pragma unroll
        for (int j = 0; j < 8; j++) f[j] = bf2f((unsigned short)v[j]);
    } else {
        const float* p = (const float*)srcv + (size_t)ms * 512 + lane * 8;
        f32x4 v0 = *(const f32x4*)p;
        f32x4 v1 = *(const f32x4*)(p + 4);
#pragma unroll
        for (int j = 0; j < 4; j++) { f[j] = v0[j]; f[j + 4] = v1[j]; }
    }
#pragma unroll
    for (int j = 0; j < 8; j++) { sum += f[j]; sq += f[j] * f[j]; }
#pragma unroll
    for (int o = 1; o < 64; o <<= 1) { sum += __shfl_xor(sum, o); sq += __shfl_xor(sq, o); }
    float mean = sum * (1.f / 512.f);
    float rstd = rsqrtf(sq * (1.f / 512.f) - mean * mean + 1e-5f);
    const float* gp = gam + lane * 8;
    const float* bp = bet + lane * 8;
    f32x4 g0 = *(const f32x4*)gp, g1 = *(const f32x4*)(gp + 4);
    f32x4 b0 = *(const f32x4*)bp, b1 = *(const f32x4*)(bp + 4);
    short8 ov;
#pragma unroll
    for (int j = 0; j < 4; j++) {
        ov[j]     = (short)f2bf((f[j] - mean) * rstd * g0[j] + b0[j]);
        ov[j + 4] = (short)f2bf((f[j + 4] - mean) * rstd * g1[j] + b1[j]);
    }
    *(short8*)(dst + (size_t)m * 512 + lane * 8) = ov;
}

// ------ 256x128 MFMA GEMM, 3-buffer rotation, ONE barrier/K-step ---------
// out = A(M x K) @ Wt(N x K)^T + bias.  4 waves x (128x64), acc 8x4.
// LDS 72KB (2 blocks/CU); 32 MFMA per barrier (2x the R14 work/step).
// Invariant: STAGE target (tt+2)%3 was read at step tt-1; top-of-step
// barrier certifies all waves past tt-1 -> single barrier per step.
// vmcnt(6) keeps next tile's 6 loads in flight (counted, never drains).
// EPI: 0 = none, 1 = exact GELU, 2 = +roll(+32) residual (extra = x fp32),
//      3 = +residual (extra = x1, fp32 or bf16 per RESBF16)
// launch_bounds(256,2): VGPR cap 256 (acc=128 needs it; cap 128 spills, R10).
template <int N, int K, int EPI, bool OUTF32, bool RESBF16>
__global__ __launch_bounds__(256, 2)
void gemm_kernel(const unsigned short* __restrict__ A,
                 const unsigned short* __restrict__ Wt,
                 const float* __restrict__ bias,
                 void* __restrict__ outv,
                 const void* __restrict__ extra, int nwg) {
    // buf b: A[256][32] at b*12288, B[128][32] at b*12288 + 8192 (ushorts)
    __shared__ __attribute__((aligned(16))) unsigned short smem[36864];  // 72 KB
    // T1: XCD-aware swizzle (grids are multiples of 8; bijective)
    int cpx = nwg >> 3;
    int bid = (blockIdx.x & 7) * cpx + (blockIdx.x >> 3);
    const int nbx = N / 128;
    int bcol = bid % nbx, brow = bid / nbx;
    int m0 = brow << 8, n0 = bcol << 7;
    int t = threadIdx.x, lane = t & 63, wid = t >> 6;
    int wr = (wid >> 1) << 7;        // wave row block (0 / 128)
    int wc = (wid & 1) << 6;         // wave col block (0 / 64)
    int rsel = lane & 15, qq = lane >> 4;
    int slotr = ((qq ^ (rsel & 3)) << 3);   // swizzled 16B slot (ushorts)

    // staging chunks: A = 4/thread (c = t + i*256, row = c>>2), B = 2/thread
    int ar[4], as_[4];
#pragma unroll
    for (int i = 0; i < 4; i++) {
        int c = t + i * 256;
        ar[i] = c >> 2;
        as_[i] = (((c & 3) ^ ((c >> 2) & 3)) << 3);   // pre-swizzled src slot
    }

#define GLD(src, dst) __builtin_amdgcn_global_load_lds(                         \
        (const __attribute__((address_space(1))) void*)(src),                  \
        (__attribute__((address_space(3))) void*)(dst), 16, 0, 0)

    auto STAGE = [&](int buf, int k0) {
        unsigned short* base = smem + buf * 12288;
#pragma unroll
        for (int i = 0; i < 4; i++)
            GLD(A + (size_t)(m0 + ar[i]) * K + k0 + as_[i], base + (t + i * 256) * 8);
#pragma unroll
        for (int i = 0; i < 2; i++)
            GLD(Wt + (size_t)(n0 + ar[i]) * K + k0 + as_[i], base + 8192 + (t + i * 256) * 8);
    };

    f32x4 zero4 = {0.f, 0.f, 0.f, 0.f};
    f32x4 acc[8][4];
#pragma unroll
    for (int mi = 0; mi < 8; mi++)
#pragma unroll
        for (int ni = 0; ni < 4; ni++) acc[mi][ni] = zero4;

    const int NT = K / 32;
    STAGE(0, 0);               // tile 0 (6 loads)
    STAGE(1, 32);              // tile 1 (12 outstanding)
    for (int tt = 0; tt < NT; tt++) {
        int cur = tt % 3;
        if (tt < NT - 1) asm volatile("s_waitcnt vmcnt(6)" ::: "memory");  // tile tt landed
        else             asm volatile("s_waitcnt vmcnt(0)" ::: "memory");
        __builtin_amdgcn_sched_barrier(0);
        __builtin_amdgcn_s_barrier();          // tile tt ready; all waves past tt-1
        __builtin_amdgcn_sched_barrier(0);
        if (tt + 2 < NT) STAGE((tt + 2) % 3, (tt + 2) * 32);   // refill buf read at tt-1
        const unsigned short* aB = smem + cur * 12288;
        const unsigned short* bB = aB + 8192;
        short8 af[8], bf4[4];
#pragma unroll
        for (int mi = 0; mi < 8; mi++)
            af[mi] = *(const short8*)(aB + (wr + mi * 16 + rsel) * 32 + slotr);
#pragma unroll
        for (int ni = 0; ni < 4; ni++)
            bf4[ni] = *(const short8*)(bB + (wc + ni * 16 + rsel) * 32 + slotr);
#pragma unroll
        for (int mi = 0; mi < 8; mi++)
#pragma unroll
            for (int ni = 0; ni < 4; ni++)
                acc[mi][ni] = __builtin_amdgcn_mfma_f32_16x16x32_bf16(af[mi], bf4[ni], acc[mi][ni], 0, 0, 0);
    }
    __builtin_amdgcn_s_barrier();              // all reads done before LDS reuse
#undef GLD

    // epilogue: C/D layout col = lane&15, row = (lane>>4)*4 + j  [m89/m91]
    int jbase = qq << 2;
    if (!OUTF32) {
        // per-wave private 128x64 LDS tile (wave-local; swizzle col^(qq<<4))
        unsigned short* ep = smem + wid * 8192;
#pragma unroll
        for (int ni = 0; ni < 4; ni++) {
            float bv = bias[n0 + wc + ni * 16 + rsel];
            int cswz = ((ni ^ qq) << 4) + rsel;
#pragma unroll
            for (int mi = 0; mi < 8; mi++)
#pragma unroll
                for (int j = 0; j < 4; j++) {
                    float v = acc[mi][ni][j] + bv;
                    if (EPI == 1) v = 0.5f * v * (1.f + erff(v * 0.70710678118654752f));
                    ep[(mi * 16 + jbase + j) * 64 + cswz] = f2bf(v);
                }
        }
        unsigned short* outp = (unsigned short*)outv;
#pragma unroll
        for (int it = 0; it < 16; it++) {
            int chunk = it * 64 + lane;              // 1024 chunks (128 rows x 8)
            int rr = chunk >> 3, c8 = (chunk & 7) << 3;
            int g = (rr >> 2) & 3;
            short8 vv = *(const short8*)(ep + rr * 64 + (c8 ^ (g << 4)));
            int grow = m0 + wr + rr, gcol = n0 + wc + c8;
            if (EPI == 2) {
                int orow = (grow & ~4095) | ((grow + SHIFT_) & 4095);
                const float* xr = (const float*)extra + (size_t)orow * N + gcol;
                f32x4 x0 = *(const f32x4*)xr, x1v = *(const f32x4*)(xr + 4);
                short8 ov;
#pragma unroll
                for (int e = 0; e < 4; e++) {
                    ov[e]     = (short)f2bf(bf2f((unsigned short)vv[e]) + x0[e]);
                    ov[e + 4] = (short)f2bf(bf2f((unsigned short)vv[e + 4]) + x1v[e]);
                }
                *(short8*)(outp + (size_t)orow * N + gcol) = ov;
            } else {
                *(short8*)(outp + (size_t)grow * N + gcol) = vv;
            }
        }
    } else {
        // fp32: 16 lanes x 4B = 64B contiguous runs — sector-aligned
#pragma unroll
        for (int ni = 0; ni < 4; ni++) {
            int gcol = n0 + wc + ni * 16 + rsel;
            float bv = bias[gcol];
#pragma unroll
            for (int mi = 0; mi < 8; mi++) {
#pragma unroll
                for (int j = 0; j < 4; j++) {
                    int grow = m0 + wr + mi * 16 + jbase + j;
                    float v = acc[mi][ni][j] + bv;
                    size_t oidx;
                    if (EPI == 2) {
                        int orow = (grow & ~4095) | ((grow + SHIFT_) & 4095);  // roll +32
                        oidx = (size_t)orow * N + gcol;
                        v += ((const float*)extra)[oidx];
                    } else {
                        oidx = (size_t)grow * N + gcol;
                        if (EPI == 3)
                            v += RESBF16 ? bf2f(((const unsigned short*)extra)[oidx])
                                         : ((const float*)extra)[oidx];
                    }
                    ((float*)outv)[oidx] = v;
                }
            }
        }
    }
}

// ---------------- MFMA window attention: one wave per (window, head) ------
// Block = 4 consecutive heads of ONE window -> 128 contiguous output cols;
// output staged in LDS and stored as 256B segments (write-amp fix).
__global__ __launch_bounds__(256, 2)
void attn_kernel(const unsigned short* __restrict__ qkv,
                 const float* __restrict__ relb,
                 unsigned short* __restrict__ obuf) {
    __shared__ __attribute__((aligned(16))) unsigned short Pl[4][64 * 72];
    __shared__ __attribute__((aligned(16))) unsigned short Vt[4][32 * 72];
    __shared__ float biasd[4][128];
    int t = threadIdx.x;
    int wid = t >> 6, lane = t & 63;
    int win = blockIdx.x >> 2;            // 512 windows
    int h0 = (blockIdx.x & 3) << 2;       // first head of this block
    int h = h0 + wid;
    const unsigned short* base = qkv + (size_t)win * 98304 + h * 32;

    float* bd = biasd[wid];
    bd[lane] = relb[lane * 16 + h];
    if (lane < 63) bd[lane + 64] = relb[(lane + 64) * 16 + h];

    int rsel = lane & 15, ksel = (lane >> 4) << 3;
    short8 qf[4], kf[4];
#pragma unroll
    for (int i = 0; i < 4; i++) {
        qf[i] = *(const short8*)(base + (size_t)(i * 16 + rsel) * 1536 + ksel);
        kf[i] = *(const short8*)(base + (size_t)(i * 16 + rsel) * 1536 + 512 + ksel);
    }
    f32x4 zero4 = {0.f, 0.f, 0.f, 0.f};
    f32x4 accS[4][4];
#pragma unroll
    for (int mi = 0; mi < 4; mi++)
#pragma unroll
        for (int ni = 0; ni < 4; ni++) accS[mi][ni] = zero4;
#pragma unroll
    for (int mi = 0; mi < 4; mi++)
#pragma unroll
        for (int ni = 0; ni < 4; ni++)
            accS[mi][ni] = __builtin_amdgcn_mfma_f32_16x16x32_bf16(qf[mi], kf[ni], accS[mi][ni], 0, 0, 0);

    // stage V^T into LDS: vt[d][k] = v[k][d], padded stride 72
    unsigned short* vt = Vt[wid];
#pragma unroll 8
    for (int it = 0; it < 32; it++) {
        int idx = (it << 6) + lane;
        int vr = idx >> 5, vd = idx & 31;
        vt[vd * 72 + vr] = base[(size_t)vr * 1536 + 1024 + vd];
    }
    __syncthreads();

    const float scale = 0.17677669529663687f;  // 1/sqrt(32)
    bool masked = ((win & 63) == 63);
    int jbase = (lane >> 4) << 2;
    float rs[4][4];
#pragma unroll
    for (int mi = 0; mi < 4; mi++) {
#pragma unroll
        for (int ni = 0; ni < 4; ni++) {
            int colb = ni * 16 + rsel;
#pragma unroll
            for (int j = 0; j < 4; j++) {
                int row = mi * 16 + jbase + j;
                float v = accS[mi][ni][j] * scale + bd[row - colb + 63];
                if (masked && ((row < 32) != (colb < 32))) v -= 100.f;
                accS[mi][ni][j] = v;
            }
        }
#pragma unroll
        for (int j = 0; j < 4; j++) {
            float m = fmaxf(fmaxf(accS[mi][0][j], accS[mi][1][j]),
                            fmaxf(accS[mi][2][j], accS[mi][3][j]));
            m = fmaxf(m, __shfl_xor(m, 1));
            m = fmaxf(m, __shfl_xor(m, 2));
            m = fmaxf(m, __shfl_xor(m, 4));
            m = fmaxf(m, __shfl_xor(m, 8));
            float ssum = 0.f;
#pragma unroll
            for (int ni = 0; ni < 4; ni++) {
                float p = __expf(accS[mi][ni][j] - m);
                accS[mi][ni][j] = p; ssum += p;
            }
            ssum += __shfl_xor(ssum, 1);
            ssum += __shfl_xor(ssum, 2);
            ssum += __shfl_xor(ssum, 4);
            ssum += __shfl_xor(ssum, 8);
            rs[mi][j] = 1.f / ssum;
        }
    }
    unsigned short* pl = Pl[wid];
#pragma unroll
    for (int mi = 0; mi < 4; mi++)
#pragma unroll
        for (int ni = 0; ni < 4; ni++)
#pragma unroll
            for (int j = 0; j < 4; j++)
                pl[(mi * 16 + jbase + j) * 72 + ni * 16 + rsel] = f2bf(accS[mi][ni][j] * rs[mi][j]);
    __syncthreads();

    f32x4 accO[4][2];
#pragma unroll
    for (int mi = 0; mi < 4; mi++) { accO[mi][0] = zero4; accO[mi][1] = zero4; }
#pragma unroll
    for (int kk = 0; kk < 2; kk++) {
        short8 pa[4], vb[2];
#pragma unroll
        for (int mi = 0; mi < 4; mi++)
            pa[mi] = *(const short8*)(pl + (mi * 16 + rsel) * 72 + (kk << 5) + ksel);
#pragma unroll
        for (int ni = 0; ni < 2; ni++)
            vb[ni] = *(const short8*)(vt + (ni * 16 + rsel) * 72 + (kk << 5) + ksel);
#pragma unroll
        for (int mi = 0; mi < 4; mi++)
#pragma unroll
            for (int ni = 0; ni < 2; ni++)
                accO[mi][ni] = __builtin_amdgcn_mfma_f32_16x16x32_bf16(pa[mi], vb[ni], accO[mi][ni], 0, 0, 0);
    }
    // ---- coalesced output: stage block's 64x128 tile in LDS (reuse Pl) ----
    __syncthreads();                                   // all waves done PV-reading Pl
    unsigned short* ot = (unsigned short*)Pl;          // [64][140] padded
    int colb = wid * 32;
#pragma unroll
    for (int mi = 0; mi < 4; mi++)
#pragma unroll
        for (int ni = 0; ni < 2; ni++)
#pragma unroll
            for (int j = 0; j < 4; j++)
                ot[(mi * 16 + jbase + j) * 140 + colb + ni * 16 + rsel] = f2bf(accO[mi][ni][j]);
    __syncthreads();
    unsigned short* ob = obuf + (size_t)win * 32768 + h0 * 32;
#pragma unroll
    for (int it = 0; it < 4; it++) {
        int chunk = it * 256 + t;
        int row = chunk >> 4, c8 = (chunk & 15) << 3;
        short8 vv = *(const short8*)(ot + row * 140 + c8);
        *(short8*)(ob + (size_t)row * 512 + c8) = vv;
    }
}

extern "C" void kernel_launch(void* const* d_in, const int* in_sizes, int n_in,
                              void* d_out, int out_size, void* d_ws, size_t ws_size,
                              hipStream_t stream) {
    (void)in_sizes; (void)n_in; (void)out_size;
    const float* x       = (const float*)d_in[0];
    const float* norm1_g = (const float*)d_in[1];
    const float* norm1_b = (const float*)d_in[2];
    const float* qkv_w   = (const float*)d_in[3];
    const float* qkv_b   = (const float*)d_in[4];
    const float* rel_b   = (const float*)d_in[5];
    const float* proj_w  = (const float*)d_in[6];
    const float* proj_b  = (const float*)d_in[7];
    const float* norm2_g = (const float*)d_in[8];
    const float* norm2_b = (const float*)d_in[9];
    const float* fc1_w   = (const float*)d_in[10];
    const float* fc1_b   = (const float*)d_in[11];
    const float* fc2_w   = (const float*)d_in[12];
    const float* fc2_b   = (const float*)d_in[13];

    char* ws = (char*)d_ws;
    unsigned short* hn   = (unsigned short*)(ws);                 // 32768x512 bf16; reused: obuf, then h2
    unsigned short* qkvb = (unsigned short*)(ws + 33554432);      // 32768x1536 bf16; reused as g1
    unsigned short* obuf = hn;                                    // alias: hn dead after QKV GEMM
    unsigned short* wq   = (unsigned short*)(ws + 167772160);     // contiguous weight block (6 MB)
    unsigned short* wp   = (unsigned short*)(ws + 167772160 + 1572864);
    unsigned short* w1   = (unsigned short*)(ws + 167772160 + 1572864 + 524288);
    unsigned short* w2   = (unsigned short*)(ws + 167772160 + 1572864 + 524288 + 2097152);
    unsigned short* x1b  = (unsigned short*)(ws + 174063616);     // 33.5 MB bf16 x1 (if ws allows)
    float* x1f           = (float*)d_out;                         // fallback: x1 fp32 in d_out
    float* outf          = (float*)d_out;
    bool bf16x1 = ws_size >= 207618048ull;                        // 174 MB + 33.5 MB

    // 0. all weights fp32 -> bf16 in ONE dispatch (wq..w2 contiguous)
    f2bf_all<<<3072, 256, 0, stream>>>(qkv_w, proj_w, fc1_w, fc2_w, wq);
    // 1. h = roll(LN1(x), -32)
    ln_kernel<false><<<8192, 256, 0, stream>>>(x, norm1_g, norm1_b, hn, SHIFT_);
    // 2. qkv = h @ qkv_w^T + qkv_b   (bf16 out)
    gemm_kernel<1536, 512, 0, false, false><<<1536, 256, 0, stream>>>(hn, wq, qkv_b, qkvb, nullptr, 1536);
    // 3. windowed attention (obuf aliases hn)
    attn_kernel<<<2048, 256, 0, stream>>>(qkvb, rel_b, obuf);
    if (bf16x1) {
        // 4. x1 = x + roll(o @ proj_w^T + proj_b, +32)   (bf16 -> x1b)
        gemm_kernel<512, 512, 2, false, false><<<512, 256, 0, stream>>>(obuf, wp, proj_b, x1b, x, 512);
        // 5. h2 = LN2(x1b)
        ln_kernel<true><<<8192, 256, 0, stream>>>(x1b, norm2_g, norm2_b, hn, 0);
        // 6. g1 = gelu(h2 @ fc1_w^T + fc1_b)
        gemm_kernel<2048, 512, 1, false, false><<<2048, 256, 0, stream>>>(hn, w1, fc1_b, qkvb, nullptr, 2048);
        // 7. out = x1b + g1 @ fc2_w^T + fc2_b   (fp32 -> d_out)
        gemm_kernel<512, 2048, 3, true, true><<<512, 256, 0, stream>>>(qkvb, w2, fc2_b, outf, x1b, 512);
    } else {
        // fallback: x1 fp32 in d_out
        gemm_kernel<512, 512, 2, true, false><<<512, 256, 0, stream>>>(obuf, wp, proj_b, x1f, x, 512);
        ln_kernel<false><<<8192, 256, 0, stream>>>(x1f, norm2_g, norm2_b, hn, 0);
        gemm_kernel<2048, 512, 1, false, false><<<2048, 256, 0, stream>>>(hn, w1, fc1_b, qkvb, nullptr, 2048);
        gemm_kernel<512, 2048, 3, true, false><<<512, 256, 0, stream>>>(qkvb, w2, fc2_b, outf, x1f, 512);
    }
}

// Round 17
// 363.484 us; speedup vs baseline: 1.0832x; 1.0472x over previous
//
#include <hip/hip_runtime.h>
#include <hip/hip_bf16.h>

typedef short short8 __attribute__((ext_vector_type(8)));
typedef short short4v __attribute__((ext_vector_type(4)));
typedef float f32x4 __attribute__((ext_vector_type(4)));

#define SHIFT_ 32

__device__ __forceinline__ float bf2f(unsigned short u) {
    union { unsigned int i; float f; } z; z.i = ((unsigned)u) << 16; return z.f;
}
__device__ __forceinline__ unsigned short f2bf(float f) {
    union { float f; unsigned int i; } z; z.f = f;
    unsigned int x = z.i;
    x += 0x7fffu + ((x >> 16) & 1u);   // round-to-nearest-even
    return (unsigned short)(x >> 16);
}

// ------- fp32 -> bf16 weight conversion, all 4 weights in one dispatch ----
__global__ __launch_bounds__(256)
void f2bf_all(const float* __restrict__ s0, const float* __restrict__ s1,
              const float* __restrict__ s2, const float* __restrict__ s3,
              unsigned short* __restrict__ dst) {
    int b = blockIdx.x;
    const float* src; int off;
    if (b < 768)       { src = s0; off = b * 1024; }
    else if (b < 1024) { src = s1; off = (b - 768) * 1024; }
    else if (b < 2048) { src = s2; off = (b - 1024) * 1024; }
    else               { src = s3; off = (b - 2048) * 1024; }
    int i = off + threadIdx.x * 4;
    f32x4 v = *(const f32x4*)(src + i);
    short4v o;
#pragma unroll
    for (int j = 0; j < 4; j++) o[j] = (short)f2bf(v[j]);
    *(short4v*)(dst + (size_t)b * 1024 + threadIdx.x * 4) = o;
}

// ---------------- LayerNorm (+roll on source index), bf16 out -------------
template <bool BF16IN>
__global__ __launch_bounds__(256)
void ln_kernel(const void* __restrict__ srcv,
               const float* __restrict__ gam,
               const float* __restrict__ bet,
               unsigned short* __restrict__ dst, int roll) {
    int wid = threadIdx.x >> 6, lane = threadIdx.x & 63;
    int m = (blockIdx.x << 2) + wid;              // output row in [0, 32768)
    int b = m >> 12, s = m & 4095;
    int ms = (b << 12) | ((s + roll) & 4095);     // source row
    float f[8], sum = 0.f, sq = 0.f;
    if (BF16IN) {
        short8 v = *(const short8*)((const unsigned short*)srcv + (size_t)ms * 512 + lane * 8);
#pragma unroll
        for (int j = 0; j < 8; j++) f[j] = bf2f((unsigned short)v[j]);
    } else {
        const float* p = (const float*)srcv + (size_t)ms * 512 + lane * 8;
        f32x4 v0 = *(const f32x4*)p;
        f32x4 v1 = *(const f32x4*)(p + 4);
#pragma unroll
        for (int j = 0; j < 4; j++) { f[j] = v0[j]; f[j + 4] = v1[j]; }
    }
#pragma unroll
    for (int j = 0; j < 8; j++) { sum += f[j]; sq += f[j] * f[j]; }
#pragma unroll
    for (int o = 1; o < 64; o <<= 1) { sum += __shfl_xor(sum, o); sq += __shfl_xor(sq, o); }
    float mean = sum * (1.f / 512.f);
    float rstd = rsqrtf(sq * (1.f / 512.f) - mean * mean + 1e-5f);
    const float* gp = gam + lane * 8;
    const float* bp = bet + lane * 8;
    f32x4 g0 = *(const f32x4*)gp, g1 = *(const f32x4*)(gp + 4);
    f32x4 b0 = *(const f32x4*)bp, b1 = *(const f32x4*)(bp + 4);
    short8 ov;
#pragma unroll
    for (int j = 0; j < 4; j++) {
        ov[j]     = (short)f2bf((f[j] - mean) * rstd * g0[j] + b0[j]);
        ov[j + 4] = (short)f2bf((f[j + 4] - mean) * rstd * g1[j] + b1[j]);
    }
    *(short8*)(dst + (size_t)m * 512 + lane * 8) = ov;
}

// ---------- 128x128 MFMA GEMM, 3-buffer rotation, ONE barrier/K-step ------
// out = A(M x K) @ Wt(N x K)^T + bias
// EPI: 0 = none, 1 = exact GELU, 2 = +roll(+32) residual (extra = x fp32),
//      3 = +residual (extra = x1, fp32 or bf16 per RESBF16)
// Invariant: STAGE target (tt+2)%3 was last read at step tt-1; the barrier
// at top of step tt proves all waves finished step tt-1 -> refill is safe
// with a single barrier. vmcnt(4) keeps next tile's 4 loads in flight.
// NOTE: min-waves/EU stays 3 (R10: tighter bound spills the accumulator).
template <int N, int K, int EPI, bool OUTF32, bool RESBF16>
__global__ __launch_bounds__(256, 3)
void gemm_kernel(const unsigned short* __restrict__ A,
                 const unsigned short* __restrict__ Wt,
                 const float* __restrict__ bias,
                 void* __restrict__ outv,
                 const void* __restrict__ extra, int nwg) {
    __shared__ __attribute__((aligned(16))) unsigned short smem[24576];  // 48 KB
    // T1: XCD-aware swizzle (grids are multiples of 8; bijective)
    int cpx = nwg >> 3;
    int bid = (blockIdx.x & 7) * cpx + (blockIdx.x >> 3);
    const int nbx = N / 128;
    int bcol = bid % nbx, brow = bid / nbx;
    int m0 = brow << 7, n0 = bcol << 7;
    int t = threadIdx.x, lane = t & 63;
    int wr = (t >> 7) << 6;          // wave row block (0 / 64)
    int wc = ((t >> 6) & 1) << 6;    // wave col block (0 / 64)
    int rsel = lane & 15, qq = lane >> 4;
    int slotr = ((qq ^ (rsel & 3)) << 3);   // swizzled 16B slot (ushorts)

    // staging chunks (fixed per thread): c0 = t, c1 = t+256; row = c>>2
    int r0 = t >> 2;
    int s0 = (((t & 3) ^ (r0 & 3)) << 3);           // pre-swizzled source slot
    int r1 = (t + 256) >> 2;
    int s1 = ((((t + 256) & 3) ^ (r1 & 3)) << 3);

#define SAb(b) (smem + (b) * 4096)
#define SBb(b) (smem + 12288 + (b) * 4096)
#define STAGE(buf, k0)                                                                  \
    do {                                                                                \
        __builtin_amdgcn_global_load_lds(                                               \
            (const __attribute__((address_space(1))) void*)(A + (size_t)(m0 + r0) * K + (k0) + s0), \
            (__attribute__((address_space(3))) void*)(SAb(buf) + t * 8), 16, 0, 0);     \
        __builtin_amdgcn_global_load_lds(                                               \
            (const __attribute__((address_space(1))) void*)(Wt + (size_t)(n0 + r0) * K + (k0) + s0), \
            (__attribute__((address_space(3))) void*)(SBb(buf) + t * 8), 16, 0, 0);     \
        __builtin_amdgcn_global_load_lds(                                               \
            (const __attribute__((address_space(1))) void*)(A + (size_t)(m0 + r1) * K + (k0) + s1), \
            (__attribute__((address_space(3))) void*)(SAb(buf) + (t + 256) * 8), 16, 0, 0); \
        __builtin_amdgcn_global_load_lds(                                               \
            (const __attribute__((address_space(1))) void*)(Wt + (size_t)(n0 + r1) * K + (k0) + s1), \
            (__attribute__((address_space(3))) void*)(SBb(buf) + (t + 256) * 8), 16, 0, 0); \
    } while (0)

    f32x4 zero4 = {0.f, 0.f, 0.f, 0.f};
    f32x4 acc[4][4];
#pragma unroll
    for (int mi = 0; mi < 4; mi++)
#pragma unroll
        for (int ni = 0; ni < 4; ni++) acc[mi][ni] = zero4;

    const int NT = K / 32;
    STAGE(0, 0);               // tile 0
    STAGE(1, 32);              // tile 1 (8 loads outstanding)
    for (int tt = 0; tt < NT; tt++) {
        int cur = tt % 3;
        if (tt < NT - 1) asm volatile("s_waitcnt vmcnt(4)" ::: "memory");  // tile tt landed
        else             asm volatile("s_waitcnt vmcnt(0)" ::: "memory");
        __builtin_amdgcn_sched_barrier(0);
        __builtin_amdgcn_s_barrier();          // tile tt ready; all waves past step tt-1
        __builtin_amdgcn_sched_barrier(0);
        if (tt + 2 < NT) STAGE((tt + 2) % 3, (tt + 2) * 32);   // refill buf read at tt-1
        short8 af[4], bf4[4];
#pragma unroll
        for (int mi = 0; mi < 4; mi++)
            af[mi] = *(const short8*)(SAb(cur) + (wr + mi * 16 + rsel) * 32 + slotr);
#pragma unroll
        for (int ni = 0; ni < 4; ni++)
            bf4[ni] = *(const short8*)(SBb(cur) + (wc + ni * 16 + rsel) * 32 + slotr);
#pragma unroll
        for (int mi = 0; mi < 4; mi++)
#pragma unroll
            for (int ni = 0; ni < 4; ni++)
                acc[mi][ni] = __builtin_amdgcn_mfma_f32_16x16x32_bf16(af[mi], bf4[ni], acc[mi][ni], 0, 0, 0);
    }
    __builtin_amdgcn_s_barrier();              // all reads done before LDS reuse below
#undef STAGE

    // epilogue: C/D layout col = lane&15, row = (lane>>4)*4 + j  [m89/m91]
    int jbase = qq << 2;
    if (!OUTF32) {
        // per-wave private 64x64 LDS tile (wave-local; swizzle col^(quarter<<4))
        unsigned short* ep = smem + (t >> 6) * 4096;
#pragma unroll
        for (int ni = 0; ni < 4; ni++) {
            float bv = bias[n0 + wc + ni * 16 + rsel];
            int cswz = ((ni ^ qq) << 4) + rsel;
#pragma unroll
            for (int mi = 0; mi < 4; mi++)
#pragma unroll
                for (int j = 0; j < 4; j++) {
                    float v = acc[mi][ni][j] + bv;
                    if (EPI == 1) v = 0.5f * v * (1.f + erff(v * 0.70710678118654752f));
                    ep[(mi * 16 + jbase + j) * 64 + cswz] = f2bf(v);
                }
        }
        unsigned short* outp = (unsigned short*)outv;
#pragma unroll
        for (int it = 0; it < 8; it++) {
            int chunk = it * 64 + lane;
            int rr = chunk >> 3, c8 = (chunk & 7) << 3;
            int g = (rr >> 2) & 3;
            short8 vv = *(const short8*)(ep + rr * 64 + (c8 ^ (g << 4)));
            int grow = m0 + wr + rr, gcol = n0 + wc + c8;
            if (EPI == 2) {
                int orow = (grow & ~4095) | ((grow + SHIFT_) & 4095);
                const float* xr = (const float*)extra + (size_t)orow * N + gcol;
                f32x4 x0 = *(const f32x4*)xr, x1v = *(const f32x4*)(xr + 4);
                short8 ov;
#pragma unroll
                for (int e = 0; e < 4; e++) {
                    ov[e]     = (short)f2bf(bf2f((unsigned short)vv[e]) + x0[e]);
                    ov[e + 4] = (short)f2bf(bf2f((unsigned short)vv[e + 4]) + x1v[e]);
                }
                *(short8*)(outp + (size_t)orow * N + gcol) = ov;
            } else {
                *(short8*)(outp + (size_t)grow * N + gcol) = vv;
            }
        }
    } else {
        // fp32: 16 lanes x 4B = 64B contiguous runs — sector-aligned
#pragma unroll
        for (int ni = 0; ni < 4; ni++) {
            int gcol = n0 + wc + ni * 16 + rsel;
            float bv = bias[gcol];
#pragma unroll
            for (int mi = 0; mi < 4; mi++) {
#pragma unroll
                for (int j = 0; j < 4; j++) {
                    int grow = m0 + wr + mi * 16 + jbase + j;
                    float v = acc[mi][ni][j] + bv;
                    size_t oidx;
                    if (EPI == 2) {
                        int orow = (grow & ~4095) | ((grow + SHIFT_) & 4095);  // roll +32
                        oidx = (size_t)orow * N + gcol;
                        v += ((const float*)extra)[oidx];
                    } else {
                        oidx = (size_t)grow * N + gcol;
                        if (EPI == 3)
                            v += RESBF16 ? bf2f(((const unsigned short*)extra)[oidx])
                                         : ((const float*)extra)[oidx];
                    }
                    ((float*)outv)[oidx] = v;
                }
            }
        }
    }
#undef SAb
#undef SBb
}

// ---------------- MFMA window attention: one wave per (window, head) ------
// Block = 4 consecutive heads of ONE window -> 128 contiguous output cols;
// output staged in LDS and stored as 256B segments (write-amp fix).
__global__ __launch_bounds__(256, 2)
void attn_kernel(const unsigned short* __restrict__ qkv,
                 const float* __restrict__ relb,
                 unsigned short* __restrict__ obuf) {
    __shared__ __attribute__((aligned(16))) unsigned short Pl[4][64 * 72];
    __shared__ __attribute__((aligned(16))) unsigned short Vt[4][32 * 72];
    __shared__ float biasd[4][128];
    int t = threadIdx.x;
    int wid = t >> 6, lane = t & 63;
    int win = blockIdx.x >> 2;            // 512 windows
    int h0 = (blockIdx.x & 3) << 2;       // first head of this block
    int h = h0 + wid;
    const unsigned short* base = qkv + (size_t)win * 98304 + h * 32;

    float* bd = biasd[wid];
    bd[lane] = relb[lane * 16 + h];
    if (lane < 63) bd[lane + 64] = relb[(lane + 64) * 16 + h];

    int rsel = lane & 15, ksel = (lane >> 4) << 3;
    short8 qf[4], kf[4];
#pragma unroll
    for (int i = 0; i < 4; i++) {
        qf[i] = *(const short8*)(base + (size_t)(i * 16 + rsel) * 1536 + ksel);
        kf[i] = *(const short8*)(base + (size_t)(i * 16 + rsel) * 1536 + 512 + ksel);
    }
    f32x4 zero4 = {0.f, 0.f, 0.f, 0.f};
    f32x4 accS[4][4];
#pragma unroll
    for (int mi = 0; mi < 4; mi++)
#pragma unroll
        for (int ni = 0; ni < 4; ni++) accS[mi][ni] = zero4;
#pragma unroll
    for (int mi = 0; mi < 4; mi++)
#pragma unroll
        for (int ni = 0; ni < 4; ni++)
            accS[mi][ni] = __builtin_amdgcn_mfma_f32_16x16x32_bf16(qf[mi], kf[ni], accS[mi][ni], 0, 0, 0);

    // stage V^T into LDS: vt[d][k] = v[k][d], padded stride 72
    unsigned short* vt = Vt[wid];
#pragma unroll 8
    for (int it = 0; it < 32; it++) {
        int idx = (it << 6) + lane;
        int vr = idx >> 5, vd = idx & 31;
        vt[vd * 72 + vr] = base[(size_t)vr * 1536 + 1024 + vd];
    }
    __syncthreads();

    const float scale = 0.17677669529663687f;  // 1/sqrt(32)
    bool masked = ((win & 63) == 63);
    int jbase = (lane >> 4) << 2;
    float rs[4][4];
#pragma unroll
    for (int mi = 0; mi < 4; mi++) {
#pragma unroll
        for (int ni = 0; ni < 4; ni++) {
            int colb = ni * 16 + rsel;
#pragma unroll
            for (int j = 0; j < 4; j++) {
                int row = mi * 16 + jbase + j;
                float v = accS[mi][ni][j] * scale + bd[row - colb + 63];
                if (masked && ((row < 32) != (colb < 32))) v -= 100.f;
                accS[mi][ni][j] = v;
            }
        }
#pragma unroll
        for (int j = 0; j < 4; j++) {
            float m = fmaxf(fmaxf(accS[mi][0][j], accS[mi][1][j]),
                            fmaxf(accS[mi][2][j], accS[mi][3][j]));
            m = fmaxf(m, __shfl_xor(m, 1));
            m = fmaxf(m, __shfl_xor(m, 2));
            m = fmaxf(m, __shfl_xor(m, 4));
            m = fmaxf(m, __shfl_xor(m, 8));
            float ssum = 0.f;
#pragma unroll
            for (int ni = 0; ni < 4; ni++) {
                float p = __expf(accS[mi][ni][j] - m);
                accS[mi][ni][j] = p; ssum += p;
            }
            ssum += __shfl_xor(ssum, 1);
            ssum += __shfl_xor(ssum, 2);
            ssum += __shfl_xor(ssum, 4);
            ssum += __shfl_xor(ssum, 8);
            rs[mi][j] = 1.f / ssum;
        }
    }
    unsigned short* pl = Pl[wid];
#pragma unroll
    for (int mi = 0; mi < 4; mi++)
#pragma unroll
        for (int ni = 0; ni < 4; ni++)
#pragma unroll
            for (int j = 0; j < 4; j++)
                pl[(mi * 16 + jbase + j) * 72 + ni * 16 + rsel] = f2bf(accS[mi][ni][j] * rs[mi][j]);
    __syncthreads();

    f32x4 accO[4][2];
#pragma unroll
    for (int mi = 0; mi < 4; mi++) { accO[mi][0] = zero4; accO[mi][1] = zero4; }
#pragma unroll
    for (int kk = 0; kk < 2; kk++) {
        short8 pa[4], vb[2];
#pragma unroll
        for (int mi = 0; mi < 4; mi++)
            pa[mi] = *(const short8*)(pl + (mi * 16 + rsel) * 72 + (kk << 5) + ksel);
#pragma unroll
        for (int ni = 0; ni < 2; ni++)
            vb[ni] = *(const short8*)(vt + (ni * 16 + rsel) * 72 + (kk << 5) + ksel);
#pragma unroll
        for (int mi = 0; mi < 4; mi++)
#pragma unroll
            for (int ni = 0; ni < 2; ni++)
                accO[mi][ni] = __builtin_amdgcn_mfma_f32_16x16x32_bf16(pa[mi], vb[ni], accO[mi][ni], 0, 0, 0);
    }
    // ---- coalesced output: stage block's 64x128 tile in LDS (reuse Pl) ----
    __syncthreads();                                   // all waves done PV-reading Pl
    unsigned short* ot = (unsigned short*)Pl;          // [64][140] padded
    int colb = wid * 32;
#pragma unroll
    for (int mi = 0; mi < 4; mi++)
#pragma unroll
        for (int ni = 0; ni < 2; ni++)
#pragma unroll
            for (int j = 0; j < 4; j++)
                ot[(mi * 16 + jbase + j) * 140 + colb + ni * 16 + rsel] = f2bf(accO[mi][ni][j]);
    __syncthreads();
    unsigned short* ob = obuf + (size_t)win * 32768 + h0 * 32;
#pragma unroll
    for (int it = 0; it < 4; it++) {
        int chunk = it * 256 + t;
        int row = chunk >> 4, c8 = (chunk & 15) << 3;
        short8 vv = *(const short8*)(ot + row * 140 + c8);
        *(short8*)(ob + (size_t)row * 512 + c8) = vv;
    }
}

extern "C" void kernel_launch(void* const* d_in, const int* in_sizes, int n_in,
                              void* d_out, int out_size, void* d_ws, size_t ws_size,
                              hipStream_t stream) {
    (void)in_sizes; (void)n_in; (void)out_size;
    const float* x       = (const float*)d_in[0];
    const float* norm1_g = (const float*)d_in[1];
    const float* norm1_b = (const float*)d_in[2];
    const float* qkv_w   = (const float*)d_in[3];
    const float* qkv_b   = (const float*)d_in[4];
    const float* rel_b   = (const float*)d_in[5];
    const float* proj_w  = (const float*)d_in[6];
    const float* proj_b  = (const float*)d_in[7];
    const float* norm2_g = (const float*)d_in[8];
    const float* norm2_b = (const float*)d_in[9];
    const float* fc1_w   = (const float*)d_in[10];
    const float* fc1_b   = (const float*)d_in[11];
    const float* fc2_w   = (const float*)d_in[12];
    const float* fc2_b   = (const float*)d_in[13];

    char* ws = (char*)d_ws;
    unsigned short* hn   = (unsigned short*)(ws);                 // 32768x512 bf16; reused: obuf, then h2
    unsigned short* qkvb = (unsigned short*)(ws + 33554432);      // 32768x1536 bf16; reused as g1
    unsigned short* obuf = hn;                                    // alias: hn dead after QKV GEMM
    unsigned short* wq   = (unsigned short*)(ws + 167772160);     // contiguous weight block (6 MB)
    unsigned short* wp   = (unsigned short*)(ws + 167772160 + 1572864);
    unsigned short* w1   = (unsigned short*)(ws + 167772160 + 1572864 + 524288);
    unsigned short* w2   = (unsigned short*)(ws + 167772160 + 1572864 + 524288 + 2097152);
    unsigned short* x1b  = (unsigned short*)(ws + 174063616);     // 33.5 MB bf16 x1 (if ws allows)
    float* x1f           = (float*)d_out;                         // fallback: x1 fp32 in d_out
    float* outf          = (float*)d_out;
    bool bf16x1 = ws_size >= 207618048ull;                        // 174 MB + 33.5 MB

    // 0. all weights fp32 -> bf16 in ONE dispatch (wq..w2 contiguous)
    f2bf_all<<<3072, 256, 0, stream>>>(qkv_w, proj_w, fc1_w, fc2_w, wq);
    // 1. h = roll(LN1(x), -32)
    ln_kernel<false><<<8192, 256, 0, stream>>>(x, norm1_g, norm1_b, hn, SHIFT_);
    // 2. qkv = h @ qkv_w^T + qkv_b   (bf16 out, coalesced epilogue)
    gemm_kernel<1536, 512, 0, false, false><<<3072, 256, 0, stream>>>(hn, wq, qkv_b, qkvb, nullptr, 3072);
    // 3. windowed attention (obuf aliases hn)
    attn_kernel<<<2048, 256, 0, stream>>>(qkvb, rel_b, obuf);
    if (bf16x1) {
        // 4. x1 = x + roll(o @ proj_w^T + proj_b, +32)   (bf16 -> x1b)
        gemm_kernel<512, 512, 2, false, false><<<1024, 256, 0, stream>>>(obuf, wp, proj_b, x1b, x, 1024);
        // 5. h2 = LN2(x1b)
        ln_kernel<true><<<8192, 256, 0, stream>>>(x1b, norm2_g, norm2_b, hn, 0);
        // 6. g1 = gelu(h2 @ fc1_w^T + fc1_b)
        gemm_kernel<2048, 512, 1, false, false><<<4096, 256, 0, stream>>>(hn, w1, fc1_b, qkvb, nullptr, 4096);
        // 7. out = x1b + g1 @ fc2_w^T + fc2_b   (fp32 -> d_out)
        gemm_kernel<512, 2048, 3, true, true><<<1024, 256, 0, stream>>>(qkvb, w2, fc2_b, outf, x1b, 1024);
    } else {
        // fallback: x1 fp32 in d_out (R12 path)
        gemm_kernel<512, 512, 2, true, false><<<1024, 256, 0, stream>>>(obuf, wp, proj_b, x1f, x, 1024);
        ln_kernel<false><<<8192, 256, 0, stream>>>(x1f, norm2_g, norm2_b, hn, 0);
        gemm_kernel<2048, 512, 1, false, false><<<4096, 256, 0, stream>>>(hn, w1, fc1_b, qkvb, nullptr, 4096);
        gemm_kernel<512, 2048, 3, true, false><<<1024, 256, 0, stream>>>(qkvb, w2, fc2_b, outf, x1f, 1024);
    }
}